// Round 5
// baseline (3989.099 us; speedup 1.0000x reference)
//
#include <hip/hip_runtime.h>
#include <math.h>

typedef __bf16 bf16_t;
typedef bf16_t bf16x8 __attribute__((ext_vector_type(8)));
typedef float  f32x4  __attribute__((ext_vector_type(4)));
typedef unsigned long long u64_t;

#define NB 32
#define NN 512
#define NH 64
#define TSTEPS 48

#define LGKM0 asm volatile("s_waitcnt lgkmcnt(0)" ::: "memory")
#define SBAR  __builtin_amdgcn_s_barrier()
#define SCHED0 __builtin_amdgcn_sched_barrier(0)

static __device__ __forceinline__ f32x4 mfma16(bf16x8 a, bf16x8 b, f32x4 c){
  return __builtin_amdgcn_mfma_f32_16x16x32_bf16(a, b, c, 0, 0, 0);
}
static __device__ __forceinline__ void gload16(char* lds, const char* g){
  __builtin_amdgcn_global_load_lds((const __attribute__((address_space(1))) void*)g,
                                   (__attribute__((address_space(3))) void*)lds, 16, 0, 0);
}
static __device__ __forceinline__ unsigned pack2(float a, float b){
  bf16_t x = (bf16_t)a, y = (bf16_t)b;
  unsigned short ux = __builtin_bit_cast(unsigned short, x);
  unsigned short uy = __builtin_bit_cast(unsigned short, y);
  return (unsigned)ux | ((unsigned)uy << 16);
}

// ---------------- setup kernels ---------------------------------------------------
__global__ __launch_bounds__(256) void k_s2f(const float* __restrict__ S,
                                             float* __restrict__ S2f){
  int idx = blockIdx.x * 256 + threadIdx.x;
  int n = idx >> 9, m = idx & 511;
  float acc = 0.f;
  #pragma unroll 8
  for (int k = 0; k < 512; ++k) acc += S[n * 512 + k] * S[k * 512 + m];
  S2f[idx] = acc;
}

// S_cat pre-swizzled tiles: 32 rt x 8 kt tiles of 4KB (rows of S then S2)
__global__ __launch_bounds__(256) void k_prepS(const float* __restrict__ S,
                                               const float* __restrict__ S2f,
                                               char* __restrict__ dst){
  int id = blockIdx.x * 256 + threadIdx.x;       // 524288
  int r = id >> 9, k = id & 511;
  float v = (r < 512) ? S[r * 512 + k] : S2f[(r - 512) * 512 + k];
  int rt = r >> 5, rr = r & 31, kt = k >> 6, kk = k & 63;
  size_t off = ((size_t)(rt * 8 + kt)) * 4096 + (size_t)(((rr * 128 + 2 * kk)) ^ ((rr & 7) << 4));
  *(bf16_t*)(dst + off) = (bf16_t)v;
}

// folded, transposed, PLAIN weights: Wt[l][o][f], f contiguous
__global__ __launch_bounds__(256) void k_prepW(const float* __restrict__ W,
                                               bf16_t* __restrict__ Wt, int OD){
  int id = blockIdx.x * 256 + threadIdx.x;
  int total = 2 * 384 * OD;
  if (id >= total) return;
  int f = id % 384, rest = id / 384, o = rest % OD, l = rest / 384 / 0 + rest / OD;
  l = (id / 384) / OD;
  o = (id / 384) % OD;
  const float* Wl = W + (size_t)l * 384 * OD;
  float v;
  if (f < 128)      v = Wl[f * OD + o] - Wl[(256 + f) * OD + o];
  else if (f < 256) v = Wl[f * OD + o];
  else              v = 2.f * Wl[f * OD + o];
  Wt[id] = (bf16_t)v;
}

__global__ __launch_bounds__(256) void k_hinit(const float* __restrict__ h0l,
                                               float* __restrict__ hNf,
                                               bf16_t* __restrict__ hN){
  int i = (blockIdx.x * 256 + threadIdx.x) * 8;
  f32x4 a = *(const f32x4*)&h0l[i], b = *(const f32x4*)&h0l[i + 4];
  *(f32x4*)&hNf[i] = a; *(f32x4*)&hNf[i + 4] = b;
  bf16x8 v;
  #pragma unroll
  for (int q = 0; q < 4; ++q){ v[q] = (bf16_t)a[q]; v[q + 4] = (bf16_t)b[q]; }
  *(bf16x8*)&hN[i] = v;
}

// ---------------- gate kernel -----------------------------------------------------
__global__ __launch_bounds__(512, 4) void k_gate(
    const float* __restrict__ xall, int t,
    const bf16_t* __restrict__ hN, const char* __restrict__ SP,
    const bf16_t* __restrict__ Wg, const float* __restrict__ bg,
    bf16_t* __restrict__ rhN, float* __restrict__ uN, bf16_t* __restrict__ Dx)
{
  __shared__ char smem[57344];
  char* const Ab0 = smem; char* const Ab1 = smem + 8192; char* const Ab2 = smem + 16384;
  char* const Bb0 = smem + 24576; char* const Bb1 = smem + 40960;
  char* const FT = smem + 24576;          // 24KB, overlays B after diffusion
  char* const RL = smem;                  // 4KB, overlays A
  char* const UL = smem + 4096;           // 8KB

  const int L = blockIdx.x;
  const int b  = (L & 7) + (((L >> 3) >> 4) << 3);
  const int bx = (L >> 3) & 15;
  const int n0 = bx * 32;
  const int tid = threadIdx.x, lane = tid & 63, w = tid >> 6;
  const int fr = lane & 15, ko = (lane >> 4) * 8, ro = (lane >> 4) * 4;
  const int pp = tid >> 4, q4 = tid & 15;

  const float*  xs = xall + ((size_t)t * NB + b) * NN * NH;
  const bf16_t* hb = hN + (size_t)b * NN * NH;

  const int wr = w >> 2, wc = w & 3;
  f32x4 acc[2][2] = {};
  f32x4 rx0[2], rx1[2]; u64_t rh0[2], rh1[2];
  char* const Abuf[3] = { Ab0, Ab1, Ab2 };
  char* const Bbuf[2] = { Bb0, Bb1 };

  auto gloadA = [&](int kt, char* Ab){
    if (w < 4)
      gload16(Ab + w * 1024, SP + ((size_t)(bx * 8 + kt)) * 4096 + (w * 64 + lane) * 16);
    else
      gload16(Ab + 4096 + (w - 4) * 1024,
              SP + ((size_t)((16 + bx) * 8 + kt)) * 4096 + ((w - 4) * 64 + lane) * 16);
  };
  auto ldB = [&](int kt, int s){
    int m = kt * 64 + 2 * pp;
    const float* xr = xs + (size_t)m * NH + q4 * 4;
    rx0[s] = *(const f32x4*)xr; rx1[s] = *(const f32x4*)(xr + NH);
    const bf16_t* hr = hb + (size_t)m * NH + q4 * 4;
    rh0[s] = *(const u64_t*)hr; rh1[s] = *(const u64_t*)(hr + NH);
  };
  auto stB = [&](int s, char* Bb){
    int mby = 4 * pp;
    #pragma unroll
    for (int i = 0; i < 4; ++i){
      int c = q4 * 4 + i;
      *(unsigned*)(Bb + ((c * 128 + mby) ^ (((c >> 2) & 7) << 4))) = pack2(rx0[s][i], rx1[s][i]);
      int c2 = c + 64;
      unsigned uh = (unsigned)((rh0[s] >> (16 * i)) & 0xffffULL)
                  | ((unsigned)((rh1[s] >> (16 * i)) & 0xffffULL) << 16);
      *(unsigned*)(Bb + ((c2 * 128 + mby) ^ (((c2 >> 2) & 7) << 4))) = uh;
    }
  };
  auto dmm = [&](const char* Ab, const char* Bb){
    #pragma unroll
    for (int kh = 0; kh < 2; ++kh){
      int kb = 2 * (kh * 32 + ko);
      bf16x8 af[2], bf_[2];
      #pragma unroll
      for (int fm = 0; fm < 2; ++fm){
        int r = wr * 32 + fm * 16 + fr;
        af[fm] = *(const bf16x8*)(Ab + ((r * 128 + kb) ^ ((r & 7) << 4)));
      }
      #pragma unroll
      for (int fc = 0; fc < 2; ++fc){
        int c = wc * 32 + fc * 16 + fr;
        bf_[fc] = *(const bf16x8*)(Bb + ((c * 128 + kb) ^ (((c >> 2) & 7) << 4)));
      }
      #pragma unroll
      for (int fm = 0; fm < 2; ++fm)
        #pragma unroll
        for (int fc = 0; fc < 2; ++fc)
          acc[fm][fc] = mfma16(af[fm], bf_[fc], acc[fm][fc]);
    }
  };

  // prologue: A0,A1 in flight; B0 staged; stB's implicit reg-wait covers A loads
  gloadA(0, Ab0); gloadA(1, Ab1);
  SCHED0;
  ldB(0, 0); ldB(1, 1);
  stB(0, Bb0);
  LGKM0; SBAR;

  #pragma unroll
  for (int kt = 0; kt < 8; ++kt){
    if (kt < 6){
      gloadA(kt + 2, Abuf[(kt + 2) % 3]);
      SCHED0;
      ldB(kt + 2, kt & 1);
    }
    if (kt < 7) stB((kt + 1) & 1, Bbuf[(kt + 1) & 1]);
    dmm(Abuf[kt % 3], Bbuf[kt & 1]);
    LGKM0; SBAR;
  }

  // ---- feat fill (cols 0..127 = x,h) + diffusion scatter (128..383) ----
  {
    int row = tid >> 4, c8 = (tid & 15) * 8;
    char* fdst = FT + (((row * 768 + 2 * c8)) ^ ((row & 7) << 4));
    if (c8 < 64){
      const float* xr = xs + (size_t)(n0 + row) * NH + c8;
      f32x4 a = *(const f32x4*)xr, bq = *(const f32x4*)(xr + 4);
      bf16x8 v;
      #pragma unroll
      for (int q = 0; q < 4; ++q){ v[q] = (bf16_t)a[q]; v[q + 4] = (bf16_t)bq[q]; }
      *(bf16x8*)fdst = v;
    } else {
      *(bf16x8*)fdst = *(const bf16x8*)(hb + (size_t)(n0 + row) * NH + (c8 - 64));
    }
  }
  #pragma unroll
  for (int fm = 0; fm < 2; ++fm)
    #pragma unroll
    for (int fc = 0; fc < 2; ++fc)
      #pragma unroll
      for (int q = 0; q < 4; ++q){
        int dr = wr * 32 + fm * 16 + ro + q;
        int nn = dr & 31;
        int col = ((dr < 32) ? 128 : 256) + wc * 32 + fc * 16 + fr;
        *(bf16_t*)(FT + (((nn * 768 + 2 * col)) ^ ((nn & 7) << 4))) = (bf16_t)acc[fm][fc][q];
      }
  LGKM0; SBAR;

  // ---- Dx dump ----
  {
    int row = tid >> 4, d8 = (tid & 15) * 8;
    int col = (d8 < 64) ? 128 + d8 : 256 + (d8 - 64);
    bf16x8 v = *(const bf16x8*)(FT + (((row * 768 + 2 * col)) ^ ((row & 7) << 4)));
    *(bf16x8*)&Dx[((size_t)b * NN + n0 + row) * 128 + d8] = v;
  }

  // ---- dense: W direct from global, barrier-free ----
  const int wn = w & 1, wo = w >> 1;
  f32x4 gd[2] = {};
  {
    const bf16_t* W0p = Wg + (size_t)(wo * 32 + fr) * 384;
    const bf16_t* W1p = Wg + (size_t)(wo * 32 + 16 + fr) * 384;
    const int r = wn * 16 + fr;
    #pragma unroll
    for (int j = 0; j < 6; ++j)
      #pragma unroll
      for (int kh = 0; kh < 2; ++kh){
        int kofs = j * 64 + kh * 32 + ko;
        bf16x8 af = *(const bf16x8*)(FT + ((r * 768 + 2 * kofs) ^ ((r & 7) << 4)));
        gd[0] = mfma16(af, *(const bf16x8*)&W0p[kofs], gd[0]);
        gd[1] = mfma16(af, *(const bf16x8*)&W1p[kofs], gd[1]);
      }
  }

  // ---- epilogue: sigmoid; rh / u via LDS transpose tiles ----
  #pragma unroll
  for (int fo = 0; fo < 2; ++fo){
    int o = wo * 32 + fo * 16 + fr;
    float bias = bg[o];
    #pragma unroll
    for (int q = 0; q < 4; ++q){
      int nn = wn * 16 + ro + q;
      float g = 1.f / (1.f + __expf(-(gd[fo][q] + bias)));
      if (o < 64){
        float hv = (float)*(const bf16_t*)(FT + (((nn * 768 + 2 * (64 + o))) ^ ((nn & 7) << 4)));
        *(bf16_t*)(RL + ((nn * 128 + 2 * o) ^ ((nn & 7) << 4))) = (bf16_t)(g * hv);
      } else {
        *(float*)(UL + ((nn * 256 + 4 * (o - 64)) ^ ((nn & 7) << 5))) = g;
      }
    }
  }
  LGKM0; SBAR;
  if (tid < 256){
    int row = tid >> 3, o8 = (tid & 7) * 8;
    bf16x8 v = *(const bf16x8*)(RL + ((row * 128 + 2 * o8) ^ ((row & 7) << 4)));
    *(bf16x8*)&rhN[((size_t)b * NN + n0 + row) * NH + o8] = v;
  } else {
    int t2 = tid - 256;
    int row = t2 >> 3, o8 = (t2 & 7) * 8;
    int base = (row * 256 + 4 * o8) ^ ((row & 7) << 5);
    f32x4 u0 = *(const f32x4*)(UL + base);
    f32x4 u1 = *(const f32x4*)(UL + base + 16);
    size_t gi = ((size_t)b * NN + n0 + row) * NH + o8;
    *(f32x4*)&uN[gi] = u0; *(f32x4*)&uN[gi + 4] = u1;
  }
}

// ---------------- candidate kernel ------------------------------------------------
__global__ __launch_bounds__(512, 4) void k_cand(
    const float* __restrict__ xall, int t,
    const bf16_t* __restrict__ rhN, const bf16_t* __restrict__ Dx,
    const char* __restrict__ SP, const bf16_t* __restrict__ Wc,
    const float* __restrict__ bc, const float* __restrict__ uN,
    float* __restrict__ hNf, bf16_t* __restrict__ hN,
    float* __restrict__ curp, float* __restrict__ fin)
{
  __shared__ char smem[49152];
  char* const Ab0 = smem; char* const Ab1 = smem + 8192; char* const Ab2 = smem + 16384;
  char* const Bb0 = smem + 24576; char* const Bb1 = smem + 32768;
  char* const FT = smem + 24576;          // 24KB
  char* const CL = smem;                  // 8KB f32 overlays A

  const int L = blockIdx.x;
  const int b  = (L & 7) + (((L >> 3) >> 4) << 3);
  const int bx = (L >> 3) & 15;
  const int n0 = bx * 32;
  const int tid = threadIdx.x, lane = tid & 63, w = tid >> 6;
  const int fr = lane & 15, ko = (lane >> 4) * 8, ro = (lane >> 4) * 4;
  const int pp = tid >> 4, q4 = tid & 15;

  const float*  xs = xall + ((size_t)t * NB + b) * NN * NH;
  const bf16_t* rb = rhN + (size_t)b * NN * NH;

  const int wr = w >> 2, wc = w & 3;
  f32x4 ca[2] = {};
  u64_t rh0[2], rh1[2];
  char* const Abuf[3] = { Ab0, Ab1, Ab2 };
  char* const Bbuf[2] = { Bb0, Bb1 };

  auto gloadA = [&](int kt, char* Ab){
    if (w < 4)
      gload16(Ab + w * 1024, SP + ((size_t)(bx * 8 + kt)) * 4096 + (w * 64 + lane) * 16);
    else
      gload16(Ab + 4096 + (w - 4) * 1024,
              SP + ((size_t)((16 + bx) * 8 + kt)) * 4096 + ((w - 4) * 64 + lane) * 16);
  };
  auto ldB = [&](int kt, int s){
    int m = kt * 64 + 2 * pp;
    const bf16_t* rr = rb + (size_t)m * NH + q4 * 4;
    rh0[s] = *(const u64_t*)rr; rh1[s] = *(const u64_t*)(rr + NH);
  };
  auto stB = [&](int s, char* Bb){
    int mby = 4 * pp;
    #pragma unroll
    for (int i = 0; i < 4; ++i){
      int c = q4 * 4 + i;
      unsigned u = (unsigned)((rh0[s] >> (16 * i)) & 0xffffULL)
                 | ((unsigned)((rh1[s] >> (16 * i)) & 0xffffULL) << 16);
      *(unsigned*)(Bb + ((c * 128 + mby) ^ (((c >> 2) & 7) << 4))) = u;
    }
  };
  auto cmm = [&](const char* Ab, const char* Bb){
    #pragma unroll
    for (int kh = 0; kh < 2; ++kh){
      int kb = 2 * (kh * 32 + ko);
      int c = wc * 16 + fr;
      bf16x8 bf_ = *(const bf16x8*)(Bb + ((c * 128 + kb) ^ (((c >> 2) & 7) << 4)));
      #pragma unroll
      for (int fm = 0; fm < 2; ++fm){
        int r = wr * 32 + fm * 16 + fr;
        bf16x8 af = *(const bf16x8*)(Ab + ((r * 128 + kb) ^ ((r & 7) << 4)));
        ca[fm] = mfma16(af, bf_, ca[fm]);
      }
    }
  };

  gloadA(0, Ab0); gloadA(1, Ab1);
  SCHED0;
  ldB(0, 0); ldB(1, 1);
  stB(0, Bb0);
  LGKM0; SBAR;

  #pragma unroll
  for (int kt = 0; kt < 8; ++kt){
    if (kt < 6){
      gloadA(kt + 2, Abuf[(kt + 2) % 3]);
      SCHED0;
      ldB(kt + 2, kt & 1);
    }
    if (kt < 7) stB((kt + 1) & 1, Bbuf[(kt + 1) & 1]);
    cmm(Abuf[kt % 3], Bbuf[kt & 1]);
    LGKM0; SBAR;
  }

  // ---- feat fill: x (0-63), rh (64-127), Dx (128-191 / 256-319), scatter (192/320) ----
  {
    int row = tid >> 4, c8 = (tid & 15) * 8;
    char* fdst = FT + (((row * 768 + 2 * c8)) ^ ((row & 7) << 4));
    if (c8 < 64){
      const float* xr = xs + (size_t)(n0 + row) * NH + c8;
      f32x4 a = *(const f32x4*)xr, bq = *(const f32x4*)(xr + 4);
      bf16x8 v;
      #pragma unroll
      for (int q = 0; q < 4; ++q){ v[q] = (bf16_t)a[q]; v[q + 4] = (bf16_t)bq[q]; }
      *(bf16x8*)fdst = v;
    } else {
      *(bf16x8*)fdst = *(const bf16x8*)(rb + (size_t)(n0 + row) * NH + (c8 - 64));
    }
    int col = (c8 < 64) ? 128 + c8 : 256 + (c8 - 64);
    bf16x8 dv = *(const bf16x8*)&Dx[((size_t)b * NN + n0 + row) * 128 + c8];
    *(bf16x8*)(FT + (((row * 768 + 2 * col)) ^ ((row & 7) << 4))) = dv;
  }
  #pragma unroll
  for (int fm = 0; fm < 2; ++fm)
    #pragma unroll
    for (int q = 0; q < 4; ++q){
      int dr = wr * 32 + fm * 16 + ro + q;
      int nn = dr & 31;
      int col = ((dr < 32) ? 192 : 320) + wc * 16 + fr;
      *(bf16_t*)(FT + (((nn * 768 + 2 * col)) ^ ((nn & 7) << 4))) = (bf16_t)ca[fm][q];
    }
  LGKM0; SBAR;

  // ---- dense: Wc direct from global ----
  const int wn = w & 1, wo = w >> 1;
  f32x4 cd = {};
  {
    const bf16_t* Wp = Wc + (size_t)(wo * 16 + fr) * 384;
    const int r = wn * 16 + fr;
    #pragma unroll
    for (int j = 0; j < 6; ++j)
      #pragma unroll
      for (int kh = 0; kh < 2; ++kh){
        int kofs = j * 64 + kh * 32 + ko;
        bf16x8 af = *(const bf16x8*)(FT + ((r * 768 + 2 * kofs) ^ ((r & 7) << 4)));
        cd = mfma16(af, *(const bf16x8*)&Wp[kofs], cd);
      }
  }

  // ---- epilogue: tanh -> CL ----
  {
    int o = wo * 16 + fr;
    float bias = bc[o];
    #pragma unroll
    for (int q = 0; q < 4; ++q){
      int nn = wn * 16 + ro + q;
      float e = __expf(2.f * (cd[q] + bias));
      *(float*)(CL + ((nn * 256 + 4 * o) ^ ((nn & 7) << 5))) = (e - 1.f) / (e + 1.f);
    }
  }
  LGKM0; SBAR;
  if (tid < 256){
    int row = tid >> 3, o8 = (tid & 7) * 8;
    int base = (row * 256 + 4 * o8) ^ ((row & 7) << 5);
    f32x4 c0 = *(const f32x4*)(CL + base);
    f32x4 c1 = *(const f32x4*)(CL + base + 16);
    size_t gi = ((size_t)b * NN + n0 + row) * NH + o8;
    f32x4 u0 = *(const f32x4*)&uN[gi], u1 = *(const f32x4*)&uN[gi + 4];
    f32x4 h0v = *(const f32x4*)&hNf[gi], h1v = *(const f32x4*)&hNf[gi + 4];
    f32x4 n0v, n1v;
    #pragma unroll
    for (int q = 0; q < 4; ++q){
      n0v[q] = u0[q] * h0v[q] + (1.f - u0[q]) * c0[q];
      n1v[q] = u1[q] * h1v[q] + (1.f - u1[q]) * c1[q];
    }
    *(f32x4*)&hNf[gi] = n0v; *(f32x4*)&hNf[gi + 4] = n1v;
    bf16x8 hb;
    #pragma unroll
    for (int q = 0; q < 4; ++q){ hb[q] = (bf16_t)n0v[q]; hb[q + 4] = (bf16_t)n1v[q]; }
    *(bf16x8*)&hN[gi] = hb;
    float* cr = curp + (size_t)t * NB * NN * NH + gi;
    *(f32x4*)cr = n0v; *(f32x4*)(cr + 4) = n1v;
    if (t == TSTEPS - 1){
      *(f32x4*)&fin[gi] = n0v; *(f32x4*)&fin[gi + 4] = n1v;
    }
  }
}

// ---------------- host orchestration ----------------------------------------------
extern "C" void kernel_launch(void* const* d_in, const int* in_sizes, int n_in,
                              void* d_out, int out_size, void* d_ws, size_t ws_size,
                              hipStream_t stream){
  const float* inputs = (const float*)d_in[0];
  const float* h0     = (const float*)d_in[1];
  const float* S      = (const float*)d_in[2];
  const float* W_gate = (const float*)d_in[3];
  const float* b_gate = (const float*)d_in[4];
  const float* W_c    = (const float*)d_in[5];
  const float* b_c    = (const float*)d_in[6];
  float* out = (float*)d_out;
  char* ws = (char*)d_ws;

  float*  S2f = (float*) (ws + 0);          // 1048576
  char*   SP  =          ws + 1048576;      // 1048576
  bf16_t* WgT = (bf16_t*)(ws + 2097152);    // 196608
  bf16_t* WcT = (bf16_t*)(ws + 2293760);    // 98304
  float*  hNf = (float*) (ws + 2392064);    // 4194304
  bf16_t* hN  = (bf16_t*)(ws + 6586368);    // 2097152
  bf16_t* rhN = (bf16_t*)(ws + 8683520);    // 2097152
  float*  uN  = (float*) (ws + 10780672);   // 4194304
  bf16_t* Dx  = (bf16_t*)(ws + 14974976);   // 4194304 -> end 19169280

  float* finalh = out;                                 // [2][B][N*H]
  float* cur    = out + (size_t)2 * NB * NN * NH;      // [T][B][N*H]

  k_s2f<<<dim3(1024), 256, 0, stream>>>(S, S2f);
  k_prepS<<<dim3(2048), 256, 0, stream>>>(S, S2f, SP);
  k_prepW<<<dim3(384), 256, 0, stream>>>(W_gate, WgT, 128);
  k_prepW<<<dim3(192), 256, 0, stream>>>(W_c, WcT, 64);

  for (int l = 0; l < 2; ++l){
    k_hinit<<<dim3(512), 256, 0, stream>>>(h0 + (size_t)l * NB * NN * NH, hNf, hN);
    const float* xa = (l == 0) ? inputs : cur;
    const bf16_t* Wg_l = WgT + (size_t)l * 128 * 384;
    const bf16_t* Wc_l = WcT + (size_t)l * 64 * 384;
    const float* bg_l = b_gate + l * 128;
    const float* bc_l = b_c + l * 64;
    float* fin_l = finalh + (size_t)l * NB * NN * NH;
    for (int t = 0; t < TSTEPS; ++t){
      k_gate<<<dim3(512), 512, 0, stream>>>(xa, t, hN, SP, Wg_l, bg_l, rhN, uN, Dx);
      k_cand<<<dim3(512), 512, 0, stream>>>(xa, t, rhN, Dx, SP, Wc_l, bc_l, uN,
                                            hNf, hN, cur, fin_l);
    }
  }
}